// Round 1
// baseline (230.589 us; speedup 1.0000x reference)
//
#include <hip/hip_runtime.h>
#include <math.h>

#define ROW_T   8192
#define THREADS 256
#define ITEMS   32          // ROW_T / THREADS
#define EPSV    1e-4f

// padded LDS index: +1 float per 32-float chunk -> conflict-free chunk reads
__device__ __forceinline__ int pad_idx(int i) { return i + (i >> 5); }

__global__ __launch_bounds__(THREADS, 4)
void cumnorm_kernel(const float* __restrict__ x, float* __restrict__ out) {
    __shared__ float lds[ROW_T + ROW_T / 32];   // 8448 floats = 33792 B
    __shared__ float wsum[4];
    __shared__ float wssum[4];

    const int t = threadIdx.x;
    const long long rowbase = (long long)blockIdx.x * ROW_T;
    const float* __restrict__ xr = x + rowbase;
    float* __restrict__ outr = out + rowbase;

    // ---- Phase 1: coalesced global float4 loads -> padded LDS ----
    #pragma unroll
    for (int j = 0; j < 8; ++j) {
        const int fi = (j * THREADS + t) * 4;       // float index, 4-aligned
        const float4 v = *reinterpret_cast<const float4*>(xr + fi);
        lds[pad_idx(fi + 0)] = v.x;
        lds[pad_idx(fi + 1)] = v.y;
        lds[pad_idx(fi + 2)] = v.z;
        lds[pad_idx(fi + 3)] = v.w;
    }
    __syncthreads();

    // ---- Phase 2: per-thread contiguous chunk -> registers + totals ----
    float xv[ITEMS];
    float s = 0.f, ss = 0.f;
    const int cbase = t * 33;                       // pad_idx(t*32)
    #pragma unroll
    for (int j = 0; j < ITEMS; ++j) {
        const float v = lds[cbase + j];
        xv[j] = v;
        s += v;
        ss += v * v;
    }

    // ---- Phase 3: block-wide exclusive scan of (s, ss) ----
    const int lane = t & 63;
    const int wid  = t >> 6;
    float is = s, iss = ss;
    #pragma unroll
    for (int off = 1; off < 64; off <<= 1) {
        const float us  = __shfl_up(is, off);
        const float uss = __shfl_up(iss, off);
        if (lane >= off) { is += us; iss += uss; }
    }
    if (lane == 63) { wsum[wid] = is; wssum[wid] = iss; }
    __syncthreads();

    float carry_s = 0.f, carry_ss = 0.f;
    #pragma unroll
    for (int w = 0; w < 4; ++w) {
        if (w < wid) { carry_s += wsum[w]; carry_ss += wssum[w]; }
    }
    float S  = carry_s  + (is  - s);    // exclusive prefix (sum)
    float SS = carry_ss + (iss - ss);   // exclusive prefix (sum of squares)

    // ---- Phase 4: normalize chunk, write back to own LDS slots ----
    const int ebase = t * ITEMS;
    #pragma unroll
    for (int j = 0; j < ITEMS; ++j) {
        const float v = xv[j];
        S  += v;
        SS += v * v;
        const float inv  = 1.0f / (float)(ebase + j + 1);
        const float mean = S * inv;
        const float var  = fmaf(SS, inv, -(mean * mean));
        lds[cbase + j] = (v - mean) * rsqrtf(var + EPSV);
    }
    __syncthreads();

    // ---- Phase 5: coalesced float4 stores ----
    #pragma unroll
    for (int j = 0; j < 8; ++j) {
        const int fi = (j * THREADS + t) * 4;
        float4 v;
        v.x = lds[pad_idx(fi + 0)];
        v.y = lds[pad_idx(fi + 1)];
        v.z = lds[pad_idx(fi + 2)];
        v.w = lds[pad_idx(fi + 3)];
        *reinterpret_cast<float4*>(outr + fi) = v;
    }
}

extern "C" void kernel_launch(void* const* d_in, const int* in_sizes, int n_in,
                              void* d_out, int out_size, void* d_ws, size_t ws_size,
                              hipStream_t stream) {
    const float* x = (const float*)d_in[0];
    float* out = (float*)d_out;
    const int rows = out_size / ROW_T;   // 16 * 256 = 4096
    cumnorm_kernel<<<rows, THREADS, 0, stream>>>(x, out);
}